// Round 5
// baseline (400.520 us; speedup 1.0000x reference)
//
#include <hip/hip_runtime.h>
#include <math.h>

#define NB 4
#define NC 12
#define NM 2
#define NN 320
#define NHW (NN*NN)
#define NBC (NB*NC)
#define CG_TOL 1e-6f
#define NITER 10
#define CBLK 400   // blocks per batch for combine/update kernels (102400/256)

#define TWO_PI_F 6.28318530717958647692f

typedef float2 c32;

__device__ __forceinline__ c32 cmul(c32 a, c32 b){ return make_float2(a.x*b.x - a.y*b.y, a.x*b.y + a.y*b.x); }
__device__ __forceinline__ c32 cmulj(c32 a, c32 b){ return make_float2(a.x*b.x + a.y*b.y, a.x*b.y - a.y*b.x); } // conj(a)*b
__device__ __forceinline__ c32 cadd(c32 a, c32 b){ return make_float2(a.x+b.x, a.y+b.y); }
__device__ __forceinline__ c32 csub(c32 a, c32 b){ return make_float2(a.x-b.x, a.y-b.y); }
__device__ __forceinline__ c32 cscale(c32 a, float s){ return make_float2(a.x*s, a.y*s); }

// multiply a by (FWD ? conj(t) : t) — fwd/inv share one twiddle table
template<bool FWD>
__device__ __forceinline__ c32 twmul(c32 a, c32 t){
  return FWD ? make_float2(a.x*t.x + a.y*t.y, a.y*t.x - a.x*t.y)
             : make_float2(a.x*t.x - a.y*t.y, a.y*t.x + a.x*t.y);
}

__device__ __forceinline__ float wave_reduce_f(float v) {
  #pragma unroll
  for (int off = 32; off >= 1; off >>= 1) v += __shfl_xor(v, off, 64);
  return v;
}
__device__ __forceinline__ c32 wave_reduce_c(c32 v) {
  #pragma unroll
  for (int off = 32; off >= 1; off >>= 1) {
    v.x += __shfl_xor(v.x, off, 64);
    v.y += __shfl_xor(v.y, off, 64);
  }
  return v;
}

// T320[j] = cis(2*pi*j/320), j=0..255 ; T64[k] = cis(2*pi*k/64), k=0..31.
__global__ __launch_bounds__(256)
void twiddle_init(c32* __restrict__ T320, c32* __restrict__ T64)
{
  const int t = threadIdx.x;
  {
    float s, c; sincosf(TWO_PI_F * (float)t / 320.f, &s, &c);
    T320[t] = make_float2(c, s);
  }
  if (t < 32) {
    float s, c; sincosf(TWO_PI_F * (float)t / 64.f, &s, &c);
    T64[t] = make_float2(c, s);
  }
}

template<bool FWD>
__device__ __forceinline__ void radix5(c32 V[5]) {
  constexpr float C1 = 0.30901699437494745f;   // cos 72
  constexpr float S1 = 0.9510565162951535f;    // sin 72
  constexpr float C2 = -0.8090169943749475f;   // cos 144
  constexpr float S2 = 0.5877852522924731f;    // sin 144
  constexpr float sg = FWD ? -1.f : 1.f;
  const c32 w1 = make_float2(C1,  sg*S1);
  const c32 w2 = make_float2(C2,  sg*S2);
  const c32 w3 = make_float2(C2, -sg*S2);
  const c32 w4 = make_float2(C1, -sg*S1);
  c32 v0=V[0], v1=V[1], v2=V[2], v3=V[3], v4=V[4];
  V[0] = cadd(cadd(v0, v1), cadd(cadd(v2, v3), v4));
  V[1] = cadd(v0, cadd(cadd(cmul(v1,w1), cmul(v2,w2)), cadd(cmul(v3,w3), cmul(v4,w4))));
  V[2] = cadd(v0, cadd(cadd(cmul(v1,w2), cmul(v2,w4)), cadd(cmul(v3,w1), cmul(v4,w3))));
  V[3] = cadd(v0, cadd(cadd(cmul(v1,w3), cmul(v2,w1)), cadd(cmul(v3,w4), cmul(v4,w2))));
  V[4] = cadd(v0, cadd(cadd(cmul(v1,w4), cmul(v2,w3)), cadd(cmul(v3,w2), cmul(v4,w1))));
}

// One 320-pt FFT per wave-row: A[j]=x[64j+lane]; output A[k1] at lane l = X[k1+5*rev6(l)].
template<bool FWD>
__device__ __forceinline__ void fft320_one(c32 A[5], const c32 ct[4], const c32 tw[6], int lane)
{
  radix5<FWD>(A);
  #pragma unroll
  for (int k = 1; k < 5; ++k) A[k] = twmul<FWD>(A[k], ct[k-1]);
  #pragma unroll
  for (int s = 0; s < 6; ++s) {
    const int m = 32 >> s;
    const c32 w = tw[s];
    const bool up = (lane & m) != 0;
    c32 o[5];
    #pragma unroll
    for (int k = 0; k < 5; ++k) { o[k].x = __shfl_xor(A[k].x, m, 64); o[k].y = __shfl_xor(A[k].y, m, 64); }
    #pragma unroll
    for (int k = 0; k < 5; ++k) {
      c32 lo = cadd(A[k], o[k]);
      c32 hi = twmul<FWD>(csub(o[k], A[k]), w);
      A[k] = up ? hi : lo;
    }
  }
}

#define LOAD_TWIDDLES \
  c32 ct[4], tw[6]; \
  _Pragma("unroll") for (int k_ = 0; k_ < 4; ++k_) ct[k_] = T320[(k_ + 1) * lane]; \
  _Pragma("unroll") for (int s_ = 0; s_ < 6; ++s_) tw[s_] = T64[(lane & ((32 >> s_) - 1)) << s_];

// Batched 1D FFT over contiguous dim of (NBC, NN, NN). 512 threads, 8 waves, 1 row/wave.
// MASK_IN: multiply input by mask. NAT_OUT: natural-layout write (else transposed).
template<bool FWD, bool MASK_IN, bool NAT_OUT>
__global__ __launch_bounds__(512)
void fft_pass(const c32* __restrict__ in, c32* __restrict__ out,
              const float* __restrict__ mask, const float* __restrict__ flag,
              const c32* __restrict__ T320, const c32* __restrict__ T64)
{
  if (flag != nullptr && flag[0] == 0.f) return;
  __shared__ c32 tile[8][NN + 2];
  const int tid = threadIdx.x, lane = tid & 63, wv = tid >> 6;
  const int bc = blockIdx.y, r0 = blockIdx.x * 8;
  LOAD_TWIDDLES
  const int rv6 = __brev((unsigned)lane) >> 26;
  const int row = r0 + wv;
  c32 A[5];
  #pragma unroll
  for (int j = 0; j < 5; ++j) {
    const size_t idx = ((size_t)bc * NN + row) * NN + lane + 64*j;
    A[j] = in[idx];
    if constexpr (MASK_IN) A[j] = cscale(A[j], mask[idx]);
  }
  fft320_one<FWD>(A, ct, tw, lane);
  #pragma unroll
  for (int k = 0; k < 5; ++k) tile[wv][k + 5*rv6] = A[k];
  __syncthreads();
  if constexpr (!NAT_OUT) {
    #pragma unroll
    for (int it = 0; it < 5; ++it) {
      const int idx = it * 512 + tid, u = idx >> 3, d = idx & 7;
      out[((size_t)bc * NN + u) * NN + (r0 + d)] = tile[d][u];
    }
  } else {
    #pragma unroll
    for (int it = 0; it < 5; ++it) {
      const int idx = it * 512 + tid, d = idx / NN, u = idx - d * NN;
      out[((size_t)bc * NN + (r0 + d)) * NN + u] = tile[d][u];
    }
  }
}

// Fused: p_new = r + beta*p_prev (beta = rr_cur/rr_prev; p_new = r at iter 0),
// coil-combine sum_m p_new*sm, forward FFT_w, transposed write.
// Blocks with c==0 persist p_new into pout (ping-pong: pout != pin).
__global__ __launch_bounds__(512)
void fft_comb(c32* __restrict__ out, const c32* __restrict__ pin,
              const c32* __restrict__ rres, c32* __restrict__ pout,
              const c32* __restrict__ smaps,
              const float* __restrict__ rr_prev, const float* __restrict__ rr_cur,
              const float* __restrict__ flag,
              const c32* __restrict__ T320, const c32* __restrict__ T64)
{
  if (flag[0] == 0.f) return;
  __shared__ c32 tile[8][NN + 2];
  const int tid = threadIdx.x, lane = tid & 63, wv = tid >> 6;
  const int bc = blockIdx.y, r0 = blockIdx.x * 8;
  const int b = bc / NC, c = bc - b * NC;
  const bool upd = (rr_cur != nullptr);
  const float beta = upd ? rr_cur[b] / rr_prev[b] : 0.f;
  LOAD_TWIDDLES
  const int rv6 = __brev((unsigned)lane) >> 26;
  const int row = r0 + wv;
  const size_t m0 = (size_t)(b*NM + 0) * NHW, m1 = (size_t)(b*NM + 1) * NHW;
  const size_t s0o = (size_t)((b*NC + c)*NM + 0) * NHW, s1o = (size_t)((b*NC + c)*NM + 1) * NHW;
  c32 A[5];
  #pragma unroll
  for (int j = 0; j < 5; ++j) {
    const size_t h = (size_t)row * NN + lane + 64*j;
    c32 r0v = rres[m0 + h], r1v = rres[m1 + h];
    c32 p0, p1;
    if (upd) {
      p0 = cadd(r0v, cscale(pin[m0 + h], beta));
      p1 = cadd(r1v, cscale(pin[m1 + h], beta));
      if (c == 0) { pout[m0 + h] = p0; pout[m1 + h] = p1; }
    } else {
      p0 = r0v; p1 = r1v;   // iter 0: p = r = x0
    }
    A[j] = cadd(cmul(p0, smaps[s0o + h]), cmul(p1, smaps[s1o + h]));
  }
  fft320_one<true>(A, ct, tw, lane);
  #pragma unroll
  for (int k = 0; k < 5; ++k) tile[wv][k + 5*rv6] = A[k];
  __syncthreads();
  #pragma unroll
  for (int it = 0; it < 5; ++it) {
    const int idx = it * 512 + tid, u = idx >> 3, d = idx & 7;
    out[((size_t)bc * NN + u) * NN + (r0 + d)] = tile[d][u];
  }
}

// Fused k-space round trip along contiguous dim: FFT_h -> *mask -> IFFT_h -> transposed write.
__global__ __launch_bounds__(512)
void fft_mask_ifft(const c32* __restrict__ in, c32* __restrict__ out,
                   const float* __restrict__ mask, const float* __restrict__ flag,
                   const c32* __restrict__ T320, const c32* __restrict__ T64)
{
  if (flag[0] == 0.f) return;
  __shared__ c32 tile[8][NN + 2];
  const int tid = threadIdx.x, lane = tid & 63, wv = tid >> 6;
  const int bc = blockIdx.y, r0 = blockIdx.x * 8;
  LOAD_TWIDDLES
  const int rv6 = __brev((unsigned)lane) >> 26;
  const int row = r0 + wv;   // row = k_w index
  c32 A[5];
  #pragma unroll
  for (int j = 0; j < 5; ++j)
    A[j] = in[((size_t)bc * NN + row) * NN + lane + 64*j];
  fft320_one<true>(A, ct, tw, lane);
  // mask in scrambled order: k_h = k + 5*rev6(lane)
  #pragma unroll
  for (int k = 0; k < 5; ++k) {
    const int kh = k + 5*rv6;
    A[k] = cscale(A[k], mask[(size_t)bc * NHW + (size_t)kh * NN + row]);
  }
  // unscramble through wave-owned LDS row (in-wave DS ordering; no barrier)
  #pragma unroll
  for (int k = 0; k < 5; ++k) tile[wv][k + 5*rv6] = A[k];
  #pragma unroll
  for (int j = 0; j < 5; ++j) A[j] = tile[wv][lane + 64*j];
  fft320_one<false>(A, ct, tw, lane);
  #pragma unroll
  for (int k = 0; k < 5; ++k) tile[wv][k + 5*rv6] = A[k];
  __syncthreads();
  #pragma unroll
  for (int it = 0; it < 5; ++it) {
    const int idx = it * 512 + tid, u = idx >> 3, d = idx & 7;
    out[((size_t)bc * NN + u) * NN + (r0 + d)] = tile[d][u];
  }
}

// x0 = (lam/NN)*sum_c conj(sm)*img + z ; x=0, r=p=x0 ; partial |x0|^2
__global__ __launch_bounds__(256)
void init_combine(const c32* __restrict__ img, const c32* __restrict__ smaps,
                  const c32* __restrict__ z, c32* __restrict__ x,
                  c32* __restrict__ r, c32* __restrict__ p,
                  const float* __restrict__ lam, float* __restrict__ part)
{
  const int b  = blockIdx.y;
  const int hw = blockIdx.x * 256 + threadIdx.x;
  const float l0 = lam[0] * (1.f / (float)NN);
  c32 a0 = make_float2(0.f,0.f), a1 = make_float2(0.f,0.f);
  #pragma unroll
  for (int c = 0; c < NC; ++c) {
    c32 iv = img[(size_t)(b*NC + c) * NHW + hw];
    c32 s0 = smaps[(size_t)((b*NC + c)*NM + 0) * NHW + hw];
    c32 s1 = smaps[(size_t)((b*NC + c)*NM + 1) * NHW + hw];
    a0 = cadd(a0, cmulj(s0, iv));
    a1 = cadd(a1, cmulj(s1, iv));
  }
  const size_t i0 = (size_t)(b*NM + 0) * NHW + hw;
  const size_t i1 = (size_t)(b*NM + 1) * NHW + hw;
  c32 x00 = cadd(cscale(a0, l0), z[i0]);
  c32 x01 = cadd(cscale(a1, l0), z[i1]);
  x[i0] = make_float2(0.f,0.f); x[i1] = make_float2(0.f,0.f);
  r[i0] = x00; r[i1] = x01;
  p[i0] = x00; p[i1] = x01;
  float acc = x00.x*x00.x + x00.y*x00.y + x01.x*x01.x + x01.y*x01.y;
  acc = wave_reduce_f(acc);
  __shared__ float sred[4];
  const int lane = threadIdx.x & 63, wv = threadIdx.x >> 6;
  if (lane == 0) sred[wv] = acc;
  __syncthreads();
  if (threadIdx.x == 0) part[b*CBLK + blockIdx.x] = sred[0]+sred[1]+sred[2]+sred[3];
}

__global__ void reduce_init(const float* __restrict__ part, float* __restrict__ x0x0,
                            float* __restrict__ rr0, float* __restrict__ flags)
{
  const int lane = threadIdx.x & 63;
  const int b = threadIdx.x >> 6;
  float s = 0.f;
  for (int j = lane; j < CBLK; j += 64) s += part[b*CBLK + j];
  s = wave_reduce_f(s);
  if (lane == 0) { x0x0[b] = s; rr0[b] = s; }
  if (threadIdx.x == 0) flags[0] = 1.f;
}

// q = (lam/NHW)*sum_c conj(sm)*img + p ; per-block pq partials
__global__ __launch_bounds__(256)
void q_combine(const c32* __restrict__ img, const c32* __restrict__ smaps,
               const c32* __restrict__ p, c32* __restrict__ q,
               const float* __restrict__ lam, const float* __restrict__ flag,
               c32* __restrict__ pqpart)
{
  if (flag[0] == 0.f) return;
  const int b  = blockIdx.y;
  const int hw = blockIdx.x * 256 + threadIdx.x;
  const float lq = lam[0] * (1.f / (float)NHW);
  c32 a0 = make_float2(0.f,0.f), a1 = make_float2(0.f,0.f);
  #pragma unroll
  for (int c = 0; c < NC; ++c) {
    c32 iv = img[(size_t)(b*NC + c) * NHW + hw];
    c32 s0 = smaps[(size_t)((b*NC + c)*NM + 0) * NHW + hw];
    c32 s1 = smaps[(size_t)((b*NC + c)*NM + 1) * NHW + hw];
    a0 = cadd(a0, cmulj(s0, iv));
    a1 = cadd(a1, cmulj(s1, iv));
  }
  const size_t i0 = (size_t)(b*NM + 0) * NHW + hw;
  const size_t i1 = (size_t)(b*NM + 1) * NHW + hw;
  c32 p0 = p[i0], p1 = p[i1];
  c32 q0 = cadd(cscale(a0, lq), p0);
  c32 q1 = cadd(cscale(a1, lq), p1);
  q[i0] = q0; q[i1] = q1;
  c32 s = cadd(cmulj(q0, p0), cmulj(q1, p1));
  s = wave_reduce_c(s);
  __shared__ c32 sred[4];
  const int lane = threadIdx.x & 63, wv = threadIdx.x >> 6;
  if (lane == 0) sred[wv] = s;
  __syncthreads();
  if (threadIdx.x == 0)
    pqpart[b*CBLK + blockIdx.x] = cadd(cadd(sred[0], sred[1]), cadd(sred[2], sred[3]));
}

// Per-block pq re-reduction (deterministic, L2-resident) -> alpha; x += a p; r -= a q; |r|^2 partials
__global__ __launch_bounds__(256)
void update1(c32* __restrict__ x, c32* __restrict__ r,
             const c32* __restrict__ p, const c32* __restrict__ q,
             const float* __restrict__ rr_i, const c32* __restrict__ pqpart,
             const float* __restrict__ flag, float* __restrict__ part)
{
  if (flag[0] == 0.f) return;
  const int b = blockIdx.y;
  const int t = threadIdx.x;
  c32 s = make_float2(0.f, 0.f);
  for (int j = t; j < CBLK; j += 256) s = cadd(s, pqpart[b*CBLK + j]);
  s = wave_reduce_c(s);
  __shared__ c32 spq[4];
  const int lane = t & 63, wv = t >> 6;
  if (lane == 0) spq[wv] = s;
  __syncthreads();
  const c32 pqv = cadd(cadd(spq[0], spq[1]), cadd(spq[2], spq[3]));
  const float rrv = rr_i[b];
  const float den = pqv.x*pqv.x + pqv.y*pqv.y;
  const c32 alpha = make_float2(rrv * pqv.x / den, -rrv * pqv.y / den);
  const int hw = blockIdx.x * 256 + t;
  float acc = 0.f;
  #pragma unroll
  for (int m = 0; m < NM; ++m) {
    const size_t idx = (size_t)(b*NM + m) * NHW + hw;
    c32 pe = p[idx], qe = q[idx];
    c32 xe = cadd(x[idx], cmul(alpha, pe));
    c32 re = csub(r[idx], cmul(alpha, qe));
    x[idx] = xe; r[idx] = re;
    acc += re.x*re.x + re.y*re.y;
  }
  acc = wave_reduce_f(acc);
  __shared__ float sred[4];
  if (lane == 0) sred[wv] = acc;
  __syncthreads();
  if (t == 0) part[b*CBLK + blockIdx.x] = sred[0]+sred[1]+sred[2]+sred[3];
}

__global__ void reduce_rr(const float* __restrict__ part, const float* __restrict__ rr_i,
                          float* __restrict__ rr_n, const float* __restrict__ x0x0,
                          const float* __restrict__ flag_i, float* __restrict__ flag_n)
{
  const int lane = threadIdx.x & 63;
  const int b = threadIdx.x >> 6;
  __shared__ float sred[4];
  __shared__ float sx0[4];
  if (flag_i[0] == 0.f) {
    if (lane == 0) rr_n[b] = rr_i[b];
    if (threadIdx.x == 0) flag_n[0] = 0.f;
    return;
  }
  float s = 0.f;
  for (int j = lane; j < CBLK; j += 64) s += part[b*CBLK + j];
  s = wave_reduce_f(s);
  if (lane == 0) { rr_n[b] = s; sred[b] = s; sx0[b] = x0x0[b]; }
  __syncthreads();
  if (threadIdx.x == 0) {
    float mn = 1e30f;
    #pragma unroll
    for (int bb = 0; bb < NB; ++bb) mn = fminf(mn, sred[bb] / sx0[bb]);
    flag_n[0] = (mn > CG_TOL) ? 1.f : 0.f;
  }
}

extern "C" void kernel_launch(void* const* d_in, const int* in_sizes, int n_in,
                              void* d_out, int out_size, void* d_ws, size_t ws_size,
                              hipStream_t stream)
{
  const c32*  z   = (const c32*)d_in[0];
  const c32*  y   = (const c32*)d_in[1];
  const c32*  sm  = (const c32*)d_in[2];
  const float* mk = (const float*)d_in[3];
  const float* lam= (const float*)d_in[4];
  c32* x = (c32*)d_out;

  char* base = (char*)d_ws;
  size_t off = 0;
  auto walloc = [&](size_t bytes) -> void* {
    void* ptr = base + off;
    off += (bytes + 255) & ~(size_t)255;
    return ptr;
  };
  c32* buf1   = (c32*)walloc((size_t)NBC * NHW * sizeof(c32));
  c32* buf2   = (c32*)walloc((size_t)NBC * NHW * sizeof(c32));
  c32* rv     = (c32*)walloc((size_t)NB * NM * NHW * sizeof(c32));
  c32* pvA    = (c32*)walloc((size_t)NB * NM * NHW * sizeof(c32));
  c32* pvB    = (c32*)walloc((size_t)NB * NM * NHW * sizeof(c32));
  c32* qv     = (c32*)walloc((size_t)NB * NM * NHW * sizeof(c32));
  c32* pqpart = (c32*)walloc((size_t)NB * CBLK * sizeof(c32));
  float* x0x0 = (float*)walloc(NB * sizeof(float));
  float* rr   = (float*)walloc((NITER + 1) * NB * sizeof(float));
  float* flags= (float*)walloc((NITER + 1) * sizeof(float));
  float* part1= (float*)walloc((size_t)NB * CBLK * sizeof(float));
  c32* T320   = (c32*)walloc(256 * sizeof(c32));
  c32* T64    = (c32*)walloc(32 * sizeof(c32));
  (void)ws_size; (void)in_sizes; (void)n_in; (void)out_size;

  dim3 fgrid(NN / 8, NBC), fblk(512), blk(256);
  dim3 cgrid(CBLK, NB);

  twiddle_init<<<1, 256, 0, stream>>>(T320, T64);

  // ---- setup: img(buf1) = unnormalized ifft2(y * mask) ----
  fft_pass<false, true,  false><<<fgrid, fblk, 0, stream>>>(y,    buf2, mk,      nullptr, T320, T64);
  fft_pass<false, false, false><<<fgrid, fblk, 0, stream>>>(buf2, buf1, nullptr, nullptr, T320, T64);
  init_combine<<<cgrid, blk, 0, stream>>>(buf1, sm, z, x, rv, pvA, lam, part1);
  reduce_init<<<1, 256, 0, stream>>>(part1, x0x0, rr, flags);

  // ---- 10 CG iterations (6 kernels each) ----
  for (int i = 0; i < NITER; ++i) {
    const float* fl = flags + i;
    c32* pin  = (i & 1) ? pvA : pvB;        // unused at i==0 (upd=false)
    c32* pout = (i & 1) ? pvB : pvA;        // i=0: pvA (holds x0, not rewritten)
    const float* rrprev = (i > 0) ? (rr + (i-1)*NB) : rr;
    const float* rrcur  = (i > 0) ? (rr + i*NB) : nullptr;
    fft_comb<<<fgrid, fblk, 0, stream>>>(buf2, pin, rv, pout, sm, rrprev, rrcur, fl, T320, T64);
    fft_mask_ifft<<<fgrid, fblk, 0, stream>>>(buf2, buf1, mk, fl, T320, T64);
    fft_pass<false, false, true><<<fgrid, fblk, 0, stream>>>(buf1, buf2, nullptr, fl, T320, T64);
    q_combine<<<cgrid, blk, 0, stream>>>(buf2, sm, pout, qv, lam, fl, pqpart);
    update1<<<cgrid, blk, 0, stream>>>(x, rv, pout, qv, rr + i*NB, pqpart, fl, part1);
    reduce_rr<<<1, 256, 0, stream>>>(part1, rr + i*NB, rr + (i+1)*NB, x0x0, fl, flags + (i+1));
  }
}